// Round 16
// baseline (151.538 us; speedup 1.0000x reference)
//
#include <hip/hip_runtime.h>

#define F16 _Float16
typedef _Float16 f16x8 __attribute__((ext_vector_type(8)));
typedef _Float16 f16x4 __attribute__((ext_vector_type(4)));
typedef float f32x4 __attribute__((ext_vector_type(4)));
typedef float f32x16 __attribute__((ext_vector_type(16)));

#define NB    4
#define CIN   512
#define NN    4096
#define KCH   256
#define OCH   512
#define BNEPS 1e-5f
#define PSET  ((size_t)NB * NN * KCH)        // elements per partial set
#define NBNN  (NB * NN)

// async global->LDS, 16B per lane (dest = wave-uniform base + lane*16)
__device__ __forceinline__ void gl16(const F16* g, F16* l) {
    __builtin_amdgcn_global_load_lds((const __attribute__((address_space(1))) void*)g,
                                     (__attribute__((address_space(3))) void*)l, 16, 0, 0);
}

// ---------------------------------------------------------------- K/V GEMM (direct x, f16 B tile)
__global__ __launch_bounds__(256) void k_kv_gemm(
    const float* __restrict__ x,
    const float* __restrict__ key_w, const float* __restrict__ key_b,
    const float* __restrict__ gamma, const float* __restrict__ beta,
    const float* __restrict__ mean,  const float* __restrict__ var,
    const float* __restrict__ value_w, const float* __restrict__ value_b,
    F16* __restrict__ KQt, F16* __restrict__ Vg) {
    __shared__ F16 Al[128][40];
    __shared__ F16 Bst[128][40];        // [n][c] f16, 80B row stride
    int b = blockIdx.z;
    int m0 = blockIdx.y * 128;
    int n0 = blockIdx.x * 128;
    int t = threadIdx.x, w = t >> 6, l = t & 63;
    int wr = w >> 1, wc = w & 1;
    int lr = l >> 4, lc = l & 15;
    f32x4 acc[4][4];
    const f32x4 fz = {0.f, 0.f, 0.f, 0.f};
#pragma unroll
    for (int i = 0; i < 4; i++)
#pragma unroll
        for (int j = 0; j < 4; j++) acc[i][j] = fz;
    const float* xb = x + (size_t)b * CIN * NN;

    int bc = t >> 3;
    int nsub = ((t & 7) + bc) & 7;

    for (int kt = 0; kt < CIN / 32; kt++) {
        int c0 = kt * 32;
        __syncthreads();
#pragma unroll
        for (int p = 0; p < 4; p++) {
            int row = (t >> 3) + p * 32;
            int cc = (t & 7) * 4;
            int rg = m0 + row;
            const float* src = (rg < 256) ? (key_w + (size_t)rg * CIN)
                                          : (value_w + (size_t)(rg - 256) * CIN);
            float4 v = *(const float4*)&src[c0 + cc];
            f16x4 h; h[0] = (F16)v.x; h[1] = (F16)v.y; h[2] = (F16)v.z; h[3] = (F16)v.w;
            *(f16x4*)&Al[row][cc] = h;
        }
        {
            const float* xrow = xb + (size_t)(c0 + bc) * NN + n0 + nsub * 16;
#pragma unroll
            for (int p = 0; p < 4; p++) {
                float4 v = *(const float4*)&xrow[p * 4];
                int n = nsub * 16 + p * 4;
                Bst[n + 0][bc] = (F16)v.x;
                Bst[n + 1][bc] = (F16)v.y;
                Bst[n + 2][bc] = (F16)v.z;
                Bst[n + 3][bc] = (F16)v.w;
            }
        }
        __syncthreads();
        f16x8 a[4];
#pragma unroll
        for (int fi = 0; fi < 4; fi++)
            a[fi] = *(f16x8*)&Al[wr * 64 + fi * 16 + lc][lr * 8];
#pragma unroll
        for (int fj = 0; fj < 4; fj++) {
            f16x8 bb = *(f16x8*)&Bst[wc * 64 + fj * 16 + lc][lr * 8];
#pragma unroll
            for (int fi = 0; fi < 4; fi++)
                acc[fi][fj] = __builtin_amdgcn_mfma_f32_16x16x32_f16(a[fi], bb, acc[fi][fj], 0, 0, 0);
        }
    }

    if (m0 < 256) {
#pragma unroll
        for (int fi = 0; fi < 4; fi++) {
            int ch0 = m0 + wr * 64 + fi * 16 + lr * 4;
            float invs[4], mns[4], bts[4], kbs[4];
#pragma unroll
            for (int r = 0; r < 4; r++) {
                int ch = ch0 + r;
                invs[r] = gamma[ch] * rsqrtf(var[ch] + BNEPS);
                mns[r] = mean[ch]; bts[r] = beta[ch]; kbs[r] = key_b[ch];
            }
#pragma unroll
            for (int fj = 0; fj < 4; fj++) {
                int n = n0 + wc * 64 + fj * 16 + lc;
                f16x4 o;
#pragma unroll
                for (int r = 0; r < 4; r++) {
                    float v = (acc[fi][fj][r] + kbs[r] - mns[r]) * invs[r] + bts[r];
                    v = fmaxf(v, 0.0f);
                    o[r] = (F16)v;
                }
                *(f16x4*)&KQt[((size_t)b * NN + n) * KCH + ch0] = o;
            }
        }
    } else {
#pragma unroll
        for (int fi = 0; fi < 4; fi++) {
            int v0 = m0 - 256 + wr * 64 + fi * 16 + lr * 4;
#pragma unroll
            for (int fj = 0; fj < 4; fj++) {
                int n = n0 + wc * 64 + fj * 16 + lc;
#pragma unroll
                for (int r = 0; r < 4; r++) {
                    float vv = acc[fi][fj][r] + value_b[v0 + r];
                    Vg[((size_t)b * KCH + v0 + r) * NN + n] = (F16)vv;
                }
            }
        }
    }
}

// ---------------------------------------------------------------- row norms + per-block max
__global__ __launch_bounds__(256) void k_rowmax(const F16* __restrict__ KQt,
                                                float* __restrict__ Mrow,
                                                float* __restrict__ Mblk) {
    __shared__ float wmax[4];
    int t = threadIdx.x;
    int r = blockIdx.x * 64 + (t >> 2);
    int part = t & 3;
    const F16* rp = KQt + (size_t)r * KCH + part * 64;
    float ss = 0.f;
#pragma unroll
    for (int i = 0; i < 8; i++) {
        f16x8 v = *(const f16x8*)&rp[i * 8];
#pragma unroll
        for (int j = 0; j < 8; j++) { float f = (float)v[j]; ss = fmaf(f, f, ss); }
    }
    ss += __shfl_xor(ss, 1, 64);
    ss += __shfl_xor(ss, 2, 64);
    float norm = sqrtf(ss);
    if (part == 0) Mrow[r] = norm;
    float mx = norm;
#pragma unroll
    for (int off = 4; off < 64; off <<= 1) mx = fmaxf(mx, __shfl_xor(mx, off, 64));
    if ((t & 63) == 0) wmax[t >> 6] = mx;
    __syncthreads();
    if (t == 0)
        Mblk[blockIdx.x] = fmaxf(fmaxf(wmax[0], wmax[1]), fmaxf(wmax[2], wmax[3]));
}

// ---------------------------------------------------------------- flash attention
// R13 structure (64q/block, 4 waves, KVBLK=64, S=2, 512 blocks = 2/CU, 32x32
// MFMA, fixed-bound softmax, zero-register pipeline) + QK 2-chain ILP split
// + setprio around MFMA clusters (2 independent blocks/CU -> m191 regime).
__global__ __launch_bounds__(256, 2) void k_flash(const F16* __restrict__ KQt,
                                                  const F16* __restrict__ Vg,
                                                  const float* __restrict__ Mrow,
                                                  const float* __restrict__ Mblk,
                                                  F16* __restrict__ parts,
                                                  float* __restrict__ Lbuf) {
    __shared__ __align__(16) F16 Kl[64 * 256];    // 32 KB linear (src-swizzled)
    __shared__ __align__(16) F16 Vl[256 * 64];    // 32 KB linear (src-swizzled)
    __shared__ __align__(16) F16 Ps[64 * 64];     //  8 KB swizzled
    __shared__ __align__(16) float crl[64];
    int bid = blockIdx.x;
    int xcd = bid & 7;
    int b = xcd >> 1;
    int hi = bid >> 3;
    int kset = hi & 1;
    int qtile = (xcd & 1) * 32 + (hi >> 1);
    int n0 = qtile * 64;
    int kbase = kset * 2048;
    int t = threadIdx.x, w = t >> 6, l = t & 63;
    int l31 = l & 31, lh = l >> 5;
    int x7 = l31 & 7;
    int qg = w >> 1, kh = w & 1;
    const F16* kqb = KQt + (size_t)b * NN * KCH;
    const F16* vgb = Vg + (size_t)b * KCH * NN;
    const float scale = 0.0625f;

#define STAGE_K(m0_)                                                            \
    {                                                                           \
        _Pragma("unroll") for (int c = 0; c < 8; c++) {                         \
            int row = c * 8 + (t >> 5);                                         \
            gl16(kqb + (size_t)((m0_) + row) * KCH + ((t & 31) ^ (t >> 5)) * 8, \
                 &Kl[c * 2048 + w * 512]);                                      \
        }                                                                       \
    }
#define STAGE_V(m0_)                                                            \
    {                                                                           \
        _Pragma("unroll") for (int c = 0; c < 8; c++) {                         \
            int vrow = c * 32 + (t >> 3);                                       \
            gl16(vgb + (size_t)vrow * NN + (m0_) + ((t & 7) ^ ((t >> 3) & 7)) * 8, \
                 &Vl[c * 2048 + w * 512]);                                      \
        }                                                                       \
    }

    // ---- prologue: stage tile 0 (latency covered by Q/m loads below) ----
    STAGE_K(kbase);
    STAGE_V(kbase);

    f16x8 qA[16];
    {
        const F16* qp = kqb + (size_t)(n0 + qg * 32 + l31) * KCH + lh * 8;
#pragma unroll
        for (int cs = 0; cs < 16; cs++) qA[cs] = *(const f16x8*)&qp[cs * 16];
    }
    float mb;
    {
        float v = Mblk[b * 64 + l];
#pragma unroll
        for (int off = 1; off < 64; off <<= 1) v = fmaxf(v, __shfl_xor(v, off, 64));
        mb = v;
    }
    float mbv = mb * scale;
    f32x4 m4[4];
    {
        const float* mp = Mrow + (size_t)b * NN + n0 + qg * 32 + lh * 4;
#pragma unroll
        for (int g = 0; g < 4; g++) {
            f32x4 v = *(const f32x4*)&mp[g * 8];
#pragma unroll
            for (int j = 0; j < 4; j++) m4[g][j] = v[j] * mbv;
        }
    }
    f16x8 one8;
#pragma unroll
    for (int j = 0; j < 8; j++) one8[j] = (F16)1.0f;

    f32x16 acc[2][2] = {};
    f32x16 lsum = {};

    __syncthreads();                   // drain: K(0), V(0) visible

    for (int mt = 0; mt < 32; mt++) {
        // ---- QK: S(32q x 32k), contraction 256, 2 independent chains ----
        f32x16 s0 = {}, s1 = {};
        __builtin_amdgcn_s_setprio(1);
#pragma unroll
        for (int cs = 0; cs < 8; cs++) {
            f16x8 kB0 = *(f16x8*)&Kl[(kh * 32 + l31) * 256 + (((cs * 4 + lh) ^ x7) << 3)];
            f16x8 kB1 = *(f16x8*)&Kl[(kh * 32 + l31) * 256 + (((cs * 4 + 2 + lh) ^ x7) << 3)];
            s0 = __builtin_amdgcn_mfma_f32_32x32x16_f16(qA[cs * 2], kB0, s0, 0, 0, 0);
            s1 = __builtin_amdgcn_mfma_f32_32x32x16_f16(qA[cs * 2 + 1], kB1, s1, 0, 0, 0);
        }
        __builtin_amdgcn_s_setprio(0);
        // ---- P = exp((s0+s1)*scale - m_row) -> Ps ----
#pragma unroll
        for (int r = 0; r < 16; r++) {
            int row = qg * 32 + (r & 3) + 8 * (r >> 2) + 4 * lh;
            float p = __expf(fmaf(s0[r] + s1[r], scale, -m4[r >> 2][r & 3]));
            int chs = (kh * 4 + (l31 >> 3)) ^ (row & 7);
            Ps[row * 64 + chs * 8 + (l31 & 7)] = (F16)p;
        }
        __syncthreads();               // B_P: P visible; V(mt) drained; Kl dead

        // ---- prefetch K(mt+1) into Kl; PV covers its latency ----
        if (mt < 31) STAGE_K(kbase + (mt + 1) * 64);

        // ---- PV (wave's 64-v slice over 64 q) + lsum ----
        __builtin_amdgcn_s_setprio(1);
#pragma unroll
        for (int kc = 0; kc < 4; kc++) {
            f16x8 pa0 = *(f16x8*)&Ps[l31 * 64 + (((kc * 2 + lh) ^ x7) * 8)];
            f16x8 pa1 = *(f16x8*)&Ps[(32 + l31) * 64 + (((kc * 2 + lh) ^ x7) * 8)];
            if (kh == 0)
                lsum = __builtin_amdgcn_mfma_f32_32x32x16_f16(qg == 0 ? pa0 : pa1,
                                                              one8, lsum, 0, 0, 0);
#pragma unroll
            for (int vh = 0; vh < 2; vh++) {
                int vr = w * 64 + vh * 32 + l31;
                f16x8 vb = *(f16x8*)&Vl[vr * 64 + (((kc * 2 + lh) ^ x7) * 8)];
                acc[0][vh] = __builtin_amdgcn_mfma_f32_32x32x16_f16(pa0, vb, acc[0][vh], 0, 0, 0);
                acc[1][vh] = __builtin_amdgcn_mfma_f32_32x32x16_f16(pa1, vb, acc[1][vh], 0, 0, 0);
            }
        }
        __builtin_amdgcn_s_setprio(0);
        __syncthreads();               // B_end: K(mt+1) drained; Vl/Ps dead

        // ---- prefetch V(mt+1) into Vl; next QK covers its latency ----
        if (mt < 31) STAGE_V(kbase + (mt + 1) * 64);
    }
#undef STAGE_K
#undef STAGE_V

    // epilogue: broadcast lsum, write normalized partial + L = m + ln(l)
    if (kh == 0 && l31 == 0) {
#pragma unroll
        for (int r = 0; r < 16; r++)
            crl[qg * 32 + (r & 3) + 8 * (r >> 2) + 4 * lh] = lsum[r];
    }
    __syncthreads();

    F16* cb = parts + (size_t)kset * PSET + (size_t)b * NN * KCH;
#pragma unroll
    for (int qg2 = 0; qg2 < 2; qg2++) {
        f32x4 iv[4];
#pragma unroll
        for (int g = 0; g < 4; g++) {
            f32x4 lv = *(f32x4*)&crl[qg2 * 32 + g * 8 + lh * 4];
#pragma unroll
            for (int j = 0; j < 4; j++) iv[g][j] = 1.0f / lv[j];
        }
#pragma unroll
        for (int vh = 0; vh < 2; vh++) {
#pragma unroll
            for (int r = 0; r < 16; r++) {
                int n = n0 + qg2 * 32 + (r & 3) + 8 * (r >> 2) + 4 * lh;
                cb[(size_t)n * KCH + w * 64 + vh * 32 + l31] =
                    (F16)(acc[qg2][vh][r] * iv[r >> 2][r & 3]);
            }
        }
    }
    float* Lb = Lbuf + ((size_t)kset * NB + b) * NN;
    if (kh == 0 && l31 == 0) {
#pragma unroll
        for (int r = 0; r < 16; r++) {
            int n = n0 + qg * 32 + (r & 3) + 8 * (r >> 2) + 4 * lh;
            Lb[n] = m4[r >> 2][r & 3] + __logf(lsum[r]);
        }
    }
}

// ---------------------------------------------------------------- out GEMM (fused split-K merge)
__global__ __launch_bounds__(256) void k_out_gemm(const F16* __restrict__ parts,
                                                  const float* __restrict__ Lbuf,
                                                  const float* __restrict__ w_w,
                                                  const float* __restrict__ w_b,
                                                  float* __restrict__ out) {
    __shared__ F16 Al[128][40];
    __shared__ F16 Bl[128][40];
    __shared__ float lw0[128], lw1[128];
    int b = blockIdx.z;
    int m0 = blockIdx.y * 128;
    int n0 = blockIdx.x * 128;
    int t = threadIdx.x, w = t >> 6, l = t & 63;
    int wr = w >> 1, wc = w & 1;
    int lr = l >> 4, lc = l & 15;

    if (t < 128) {
        int n = n0 + t;
        float L0 = Lbuf[(size_t)b * NN + n];
        float L1 = Lbuf[(size_t)NBNN + (size_t)b * NN + n];
        float M = fmaxf(L0, L1);
        float e0 = __expf(L0 - M), e1 = __expf(L1 - M);
        float inv = 1.0f / (e0 + e1);
        lw0[t] = e0 * inv; lw1[t] = e1 * inv;
    }
    __syncthreads();
    int row0 = t >> 2, row1 = (t >> 2) + 64;
    float w00 = lw0[row0], w10 = lw1[row0];
    float w01 = lw0[row1], w11 = lw1[row1];

    f32x4 acc[4][4];
    const f32x4 fz = {0.f, 0.f, 0.f, 0.f};
#pragma unroll
    for (int i = 0; i < 4; i++)
#pragma unroll
        for (int j = 0; j < 4; j++) acc[i][j] = fz;

    for (int kt = 0; kt < KCH / 32; kt++) {
        int c0 = kt * 32;
        __syncthreads();
#pragma unroll
        for (int p = 0; p < 4; p++) {
            int row = (t >> 3) + p * 32;
            int cc = (t & 7) * 4;
            float4 v = *(const float4*)&w_w[(size_t)(m0 + row) * KCH + c0 + cc];
            f16x4 h; h[0] = (F16)v.x; h[1] = (F16)v.y; h[2] = (F16)v.z; h[3] = (F16)v.w;
            *(f16x4*)&Al[row][cc] = h;
        }
#pragma unroll
        for (int p = 0; p < 2; p++) {
            int row = (p == 0) ? row0 : row1;
            float wa = (p == 0) ? w00 : w01;
            float wb2 = (p == 0) ? w10 : w11;
            int cc = (t & 3) * 8;
            size_t base = ((size_t)b * NN + n0 + row) * KCH + c0 + cc;
            f16x8 p0 = *(const f16x8*)&parts[base];
            f16x8 p1 = *(const f16x8*)&parts[PSET + base];
            f16x8 m;
#pragma unroll
            for (int j = 0; j < 8; j++)
                m[j] = (F16)(wa * (float)p0[j] + wb2 * (float)p1[j]);
            *(f16x8*)&Bl[row][cc] = m;
        }
        __syncthreads();
        f16x8 a[4];
#pragma unroll
        for (int fi = 0; fi < 4; fi++)
            a[fi] = *(f16x8*)&Al[wr * 64 + fi * 16 + lc][lr * 8];
#pragma unroll
        for (int fj = 0; fj < 4; fj++) {
            f16x8 bb = *(f16x8*)&Bl[wc * 64 + fj * 16 + lc][lr * 8];
#pragma unroll
            for (int fi = 0; fi < 4; fi++)
                acc[fi][fj] = __builtin_amdgcn_mfma_f32_16x16x32_f16(a[fi], bb, acc[fi][fj], 0, 0, 0);
        }
    }

#pragma unroll
    for (int fi = 0; fi < 4; fi++) {
        int o0 = m0 + wr * 64 + fi * 16 + lr * 4;
#pragma unroll
        for (int fj = 0; fj < 4; fj++) {
            int n = n0 + wc * 64 + fj * 16 + lc;
#pragma unroll
            for (int r = 0; r < 4; r++) {
                out[((size_t)b * OCH + o0 + r) * NN + n] = acc[fi][fj][r] + w_b[o0 + r];
            }
        }
    }
}

// ---------------------------------------------------------------- launch
extern "C" void kernel_launch(void* const* d_in, const int* in_sizes, int n_in,
                              void* d_out, int out_size, void* d_ws, size_t ws_size,
                              hipStream_t stream) {
    const float* x       = (const float*)d_in[0];
    const float* key_w   = (const float*)d_in[1];
    const float* key_b   = (const float*)d_in[2];
    const float* gamma   = (const float*)d_in[3];
    const float* beta    = (const float*)d_in[4];
    const float* mean    = (const float*)d_in[5];
    const float* var     = (const float*)d_in[6];
    const float* value_w = (const float*)d_in[7];
    const float* value_b = (const float*)d_in[8];
    const float* w_w     = (const float*)d_in[9];
    const float* w_b     = (const float*)d_in[10];
    float* out = (float*)d_out;
    char* ws = (char*)d_ws;

    // layout: parts 2*8.39M | KQt 8.39M | Vg 8.39M | L 128K | Mrow 64K | Mblk 1K
    size_t kqt_off  = 2 * PSET * 2;
    size_t vg_off   = kqt_off + 8388608ull;
    size_t l_off    = vg_off + 8388608ull;
    size_t mrow_off = l_off + (size_t)2 * NBNN * 4;
    size_t mblk_off = mrow_off + (size_t)NBNN * 4;

    F16*   parts = (F16*)(ws);
    F16*   KQt   = (F16*)(ws + kqt_off);
    F16*   Vg    = (F16*)(ws + vg_off);
    float* Lbuf  = (float*)(ws + l_off);
    float* Mrow  = (float*)(ws + mrow_off);
    float* Mblk  = (float*)(ws + mblk_off);

    hipLaunchKernelGGL(k_kv_gemm, dim3(32, 4, 4), dim3(256), 0, stream,
                       x, key_w, key_b, gamma, beta, mean, var, value_w, value_b, KQt, Vg);
    hipLaunchKernelGGL(k_rowmax, dim3(256), dim3(256), 0, stream, KQt, Mrow, Mblk);
    hipLaunchKernelGGL(k_flash, dim3(512), dim3(256), 0, stream,
                       KQt, Vg, Mrow, Mblk, parts, Lbuf);
    hipLaunchKernelGGL(k_out_gemm, dim3(32, 4, 4), dim3(256), 0, stream,
                       parts, Lbuf, w_w, w_b, out);
}

// Round 17
// 147.113 us; speedup vs baseline: 1.0301x; 1.0301x over previous
//
#include <hip/hip_runtime.h>

#define F16 _Float16
typedef _Float16 f16x8 __attribute__((ext_vector_type(8)));
typedef _Float16 f16x4 __attribute__((ext_vector_type(4)));
typedef float f32x4 __attribute__((ext_vector_type(4)));
typedef float f32x16 __attribute__((ext_vector_type(16)));

#define NB    4
#define CIN   512
#define NN    4096
#define KCH   256
#define OCH   512
#define BNEPS 1e-5f
#define PSET  ((size_t)NB * NN * KCH)        // elements per partial set
#define NBNN  (NB * NN)

// async global->LDS, 16B per lane (dest = wave-uniform base + lane*16)
__device__ __forceinline__ void gl16(const F16* g, F16* l) {
    __builtin_amdgcn_global_load_lds((const __attribute__((address_space(1))) void*)g,
                                     (__attribute__((address_space(3))) void*)l, 16, 0, 0);
}

// ---------------------------------------------------------------- K/V GEMM (direct x, f16 B tile)
__global__ __launch_bounds__(256) void k_kv_gemm(
    const float* __restrict__ x,
    const float* __restrict__ key_w, const float* __restrict__ key_b,
    const float* __restrict__ gamma, const float* __restrict__ beta,
    const float* __restrict__ mean,  const float* __restrict__ var,
    const float* __restrict__ value_w, const float* __restrict__ value_b,
    F16* __restrict__ KQt, F16* __restrict__ Vg) {
    __shared__ F16 Al[128][40];
    __shared__ F16 Bst[128][40];        // [n][c] f16, 80B row stride
    int b = blockIdx.z;
    int m0 = blockIdx.y * 128;
    int n0 = blockIdx.x * 128;
    int t = threadIdx.x, w = t >> 6, l = t & 63;
    int wr = w >> 1, wc = w & 1;
    int lr = l >> 4, lc = l & 15;
    f32x4 acc[4][4];
    const f32x4 fz = {0.f, 0.f, 0.f, 0.f};
#pragma unroll
    for (int i = 0; i < 4; i++)
#pragma unroll
        for (int j = 0; j < 4; j++) acc[i][j] = fz;
    const float* xb = x + (size_t)b * CIN * NN;

    int bc = t >> 3;
    int nsub = ((t & 7) + bc) & 7;

    for (int kt = 0; kt < CIN / 32; kt++) {
        int c0 = kt * 32;
        __syncthreads();
#pragma unroll
        for (int p = 0; p < 4; p++) {
            int row = (t >> 3) + p * 32;
            int cc = (t & 7) * 4;
            int rg = m0 + row;
            const float* src = (rg < 256) ? (key_w + (size_t)rg * CIN)
                                          : (value_w + (size_t)(rg - 256) * CIN);
            float4 v = *(const float4*)&src[c0 + cc];
            f16x4 h; h[0] = (F16)v.x; h[1] = (F16)v.y; h[2] = (F16)v.z; h[3] = (F16)v.w;
            *(f16x4*)&Al[row][cc] = h;
        }
        {
            const float* xrow = xb + (size_t)(c0 + bc) * NN + n0 + nsub * 16;
#pragma unroll
            for (int p = 0; p < 4; p++) {
                float4 v = *(const float4*)&xrow[p * 4];
                int n = nsub * 16 + p * 4;
                Bst[n + 0][bc] = (F16)v.x;
                Bst[n + 1][bc] = (F16)v.y;
                Bst[n + 2][bc] = (F16)v.z;
                Bst[n + 3][bc] = (F16)v.w;
            }
        }
        __syncthreads();
        f16x8 a[4];
#pragma unroll
        for (int fi = 0; fi < 4; fi++)
            a[fi] = *(f16x8*)&Al[wr * 64 + fi * 16 + lc][lr * 8];
#pragma unroll
        for (int fj = 0; fj < 4; fj++) {
            f16x8 bb = *(f16x8*)&Bst[wc * 64 + fj * 16 + lc][lr * 8];
#pragma unroll
            for (int fi = 0; fi < 4; fi++)
                acc[fi][fj] = __builtin_amdgcn_mfma_f32_16x16x32_f16(a[fi], bb, acc[fi][fj], 0, 0, 0);
        }
    }

    if (m0 < 256) {
#pragma unroll
        for (int fi = 0; fi < 4; fi++) {
            int ch0 = m0 + wr * 64 + fi * 16 + lr * 4;
            float invs[4], mns[4], bts[4], kbs[4];
#pragma unroll
            for (int r = 0; r < 4; r++) {
                int ch = ch0 + r;
                invs[r] = gamma[ch] * rsqrtf(var[ch] + BNEPS);
                mns[r] = mean[ch]; bts[r] = beta[ch]; kbs[r] = key_b[ch];
            }
#pragma unroll
            for (int fj = 0; fj < 4; fj++) {
                int n = n0 + wc * 64 + fj * 16 + lc;
                f16x4 o;
#pragma unroll
                for (int r = 0; r < 4; r++) {
                    float v = (acc[fi][fj][r] + kbs[r] - mns[r]) * invs[r] + bts[r];
                    v = fmaxf(v, 0.0f);
                    o[r] = (F16)v;
                }
                *(f16x4*)&KQt[((size_t)b * NN + n) * KCH + ch0] = o;
            }
        }
    } else {
#pragma unroll
        for (int fi = 0; fi < 4; fi++) {
            int v0 = m0 - 256 + wr * 64 + fi * 16 + lr * 4;
#pragma unroll
            for (int fj = 0; fj < 4; fj++) {
                int n = n0 + wc * 64 + fj * 16 + lc;
#pragma unroll
                for (int r = 0; r < 4; r++) {
                    float vv = acc[fi][fj][r] + value_b[v0 + r];
                    Vg[((size_t)b * KCH + v0 + r) * NN + n] = (F16)vv;
                }
            }
        }
    }
}

// ---------------------------------------------------------------- row norms + per-block max
__global__ __launch_bounds__(256) void k_rowmax(const F16* __restrict__ KQt,
                                                float* __restrict__ Mrow,
                                                float* __restrict__ Mblk) {
    __shared__ float wmax[4];
    int t = threadIdx.x;
    int r = blockIdx.x * 64 + (t >> 2);
    int part = t & 3;
    const F16* rp = KQt + (size_t)r * KCH + part * 64;
    float ss = 0.f;
#pragma unroll
    for (int i = 0; i < 8; i++) {
        f16x8 v = *(const f16x8*)&rp[i * 8];
#pragma unroll
        for (int j = 0; j < 8; j++) { float f = (float)v[j]; ss = fmaf(f, f, ss); }
    }
    ss += __shfl_xor(ss, 1, 64);
    ss += __shfl_xor(ss, 2, 64);
    float norm = sqrtf(ss);
    if (part == 0) Mrow[r] = norm;
    float mx = norm;
#pragma unroll
    for (int off = 4; off < 64; off <<= 1) mx = fmaxf(mx, __shfl_xor(mx, off, 64));
    if ((t & 63) == 0) wmax[t >> 6] = mx;
    __syncthreads();
    if (t == 0)
        Mblk[blockIdx.x] = fmaxf(fmaxf(wmax[0], wmax[1]), fmaxf(wmax[2], wmax[3]));
}

// ---------------------------------------------------------------- flash attention (R13 verbatim)
// 64q/block, 4 waves, KVBLK=64, S=2, 512 blocks = 2/CU (LDS 72.3 KB), 32x32
// MFMA, fixed-bound softmax, zero-register pipeline: K(mt+1) streams into the
// dead Kl during PV; V(mt+1) streams into the dead Vl during the next QK.
__global__ __launch_bounds__(256, 2) void k_flash(const F16* __restrict__ KQt,
                                                  const F16* __restrict__ Vg,
                                                  const float* __restrict__ Mrow,
                                                  const float* __restrict__ Mblk,
                                                  F16* __restrict__ parts,
                                                  float* __restrict__ Lbuf) {
    __shared__ __align__(16) F16 Kl[64 * 256];    // 32 KB linear (src-swizzled)
    __shared__ __align__(16) F16 Vl[256 * 64];    // 32 KB linear (src-swizzled)
    __shared__ __align__(16) F16 Ps[64 * 64];     //  8 KB swizzled
    __shared__ __align__(16) float crl[64];
    int bid = blockIdx.x;
    int xcd = bid & 7;
    int b = xcd >> 1;
    int hi = bid >> 3;
    int kset = hi & 1;
    int qtile = (xcd & 1) * 32 + (hi >> 1);
    int n0 = qtile * 64;
    int kbase = kset * 2048;
    int t = threadIdx.x, w = t >> 6, l = t & 63;
    int l31 = l & 31, lh = l >> 5;
    int x7 = l31 & 7;
    int qg = w >> 1, kh = w & 1;
    const F16* kqb = KQt + (size_t)b * NN * KCH;
    const F16* vgb = Vg + (size_t)b * KCH * NN;
    const float scale = 0.0625f;

#define STAGE_K(m0_)                                                            \
    {                                                                           \
        _Pragma("unroll") for (int c = 0; c < 8; c++) {                         \
            int row = c * 8 + (t >> 5);                                         \
            gl16(kqb + (size_t)((m0_) + row) * KCH + ((t & 31) ^ (t >> 5)) * 8, \
                 &Kl[c * 2048 + w * 512]);                                      \
        }                                                                       \
    }
#define STAGE_V(m0_)                                                            \
    {                                                                           \
        _Pragma("unroll") for (int c = 0; c < 8; c++) {                         \
            int vrow = c * 32 + (t >> 3);                                       \
            gl16(vgb + (size_t)vrow * NN + (m0_) + ((t & 7) ^ ((t >> 3) & 7)) * 8, \
                 &Vl[c * 2048 + w * 512]);                                      \
        }                                                                       \
    }

    // ---- prologue: stage tile 0 (latency covered by Q/m loads below) ----
    STAGE_K(kbase);
    STAGE_V(kbase);

    f16x8 qA[16];
    {
        const F16* qp = kqb + (size_t)(n0 + qg * 32 + l31) * KCH + lh * 8;
#pragma unroll
        for (int cs = 0; cs < 16; cs++) qA[cs] = *(const f16x8*)&qp[cs * 16];
    }
    float mb;
    {
        float v = Mblk[b * 64 + l];
#pragma unroll
        for (int off = 1; off < 64; off <<= 1) v = fmaxf(v, __shfl_xor(v, off, 64));
        mb = v;
    }
    float mbv = mb * scale;
    f32x4 m4[4];
    {
        const float* mp = Mrow + (size_t)b * NN + n0 + qg * 32 + lh * 4;
#pragma unroll
        for (int g = 0; g < 4; g++) {
            f32x4 v = *(const f32x4*)&mp[g * 8];
#pragma unroll
            for (int j = 0; j < 4; j++) m4[g][j] = v[j] * mbv;
        }
    }
    f16x8 one8;
#pragma unroll
    for (int j = 0; j < 8; j++) one8[j] = (F16)1.0f;

    f32x16 acc[2][2] = {};
    f32x16 lsum = {};

    __syncthreads();                   // drain: K(0), V(0) visible

    for (int mt = 0; mt < 32; mt++) {
        // ---- QK: S(32q x 32k), contraction 256 ----
        f32x16 s = {};
#pragma unroll
        for (int cs = 0; cs < 16; cs++) {
            f16x8 kB = *(f16x8*)&Kl[(kh * 32 + l31) * 256 + (((cs * 2 + lh) ^ x7) * 8)];
            s = __builtin_amdgcn_mfma_f32_32x32x16_f16(qA[cs], kB, s, 0, 0, 0);
        }
        // ---- P = exp(S*scale - m_row) -> Ps ----
#pragma unroll
        for (int r = 0; r < 16; r++) {
            int row = qg * 32 + (r & 3) + 8 * (r >> 2) + 4 * lh;
            float p = __expf(fmaf(s[r], scale, -m4[r >> 2][r & 3]));
            int chs = (kh * 4 + (l31 >> 3)) ^ (row & 7);
            Ps[row * 64 + chs * 8 + (l31 & 7)] = (F16)p;
        }
        __syncthreads();               // B_P: P visible; V(mt) drained; Kl dead

        // ---- prefetch K(mt+1) into Kl; PV covers its latency ----
        if (mt < 31) STAGE_K(kbase + (mt + 1) * 64);

        // ---- PV (wave's 64-v slice over 64 q) + lsum ----
#pragma unroll
        for (int kc = 0; kc < 4; kc++) {
            f16x8 pa0 = *(f16x8*)&Ps[l31 * 64 + (((kc * 2 + lh) ^ x7) * 8)];
            f16x8 pa1 = *(f16x8*)&Ps[(32 + l31) * 64 + (((kc * 2 + lh) ^ x7) * 8)];
            if (kh == 0)
                lsum = __builtin_amdgcn_mfma_f32_32x32x16_f16(qg == 0 ? pa0 : pa1,
                                                              one8, lsum, 0, 0, 0);
#pragma unroll
            for (int vh = 0; vh < 2; vh++) {
                int vr = w * 64 + vh * 32 + l31;
                f16x8 vb = *(f16x8*)&Vl[vr * 64 + (((kc * 2 + lh) ^ x7) * 8)];
                acc[0][vh] = __builtin_amdgcn_mfma_f32_32x32x16_f16(pa0, vb, acc[0][vh], 0, 0, 0);
                acc[1][vh] = __builtin_amdgcn_mfma_f32_32x32x16_f16(pa1, vb, acc[1][vh], 0, 0, 0);
            }
        }
        __syncthreads();               // B_end: K(mt+1) drained; Vl/Ps dead

        // ---- prefetch V(mt+1) into Vl; next QK covers its latency ----
        if (mt < 31) STAGE_V(kbase + (mt + 1) * 64);
    }
#undef STAGE_K
#undef STAGE_V

    // epilogue: broadcast lsum, write normalized partial + L = m + ln(l)
    if (kh == 0 && l31 == 0) {
#pragma unroll
        for (int r = 0; r < 16; r++)
            crl[qg * 32 + (r & 3) + 8 * (r >> 2) + 4 * lh] = lsum[r];
    }
    __syncthreads();

    F16* cb = parts + (size_t)kset * PSET + (size_t)b * NN * KCH;
#pragma unroll
    for (int qg2 = 0; qg2 < 2; qg2++) {
        f32x4 iv[4];
#pragma unroll
        for (int g = 0; g < 4; g++) {
            f32x4 lv = *(f32x4*)&crl[qg2 * 32 + g * 8 + lh * 4];
#pragma unroll
            for (int j = 0; j < 4; j++) iv[g][j] = 1.0f / lv[j];
        }
#pragma unroll
        for (int vh = 0; vh < 2; vh++) {
#pragma unroll
            for (int r = 0; r < 16; r++) {
                int n = n0 + qg2 * 32 + (r & 3) + 8 * (r >> 2) + 4 * lh;
                cb[(size_t)n * KCH + w * 64 + vh * 32 + l31] =
                    (F16)(acc[qg2][vh][r] * iv[r >> 2][r & 3]);
            }
        }
    }
    float* Lb = Lbuf + ((size_t)kset * NB + b) * NN;
    if (kh == 0 && l31 == 0) {
#pragma unroll
        for (int r = 0; r < 16; r++) {
            int n = n0 + qg * 32 + (r & 3) + 8 * (r >> 2) + 4 * lh;
            Lb[n] = m4[r >> 2][r & 3] + __logf(lsum[r]);
        }
    }
}

// ---------------------------------------------------------------- out GEMM (fused split-K merge)
__global__ __launch_bounds__(256) void k_out_gemm(const F16* __restrict__ parts,
                                                  const float* __restrict__ Lbuf,
                                                  const float* __restrict__ w_w,
                                                  const float* __restrict__ w_b,
                                                  float* __restrict__ out) {
    __shared__ F16 Al[128][40];
    __shared__ F16 Bl[128][40];
    __shared__ float lw0[128], lw1[128];
    int b = blockIdx.z;
    int m0 = blockIdx.y * 128;
    int n0 = blockIdx.x * 128;
    int t = threadIdx.x, w = t >> 6, l = t & 63;
    int wr = w >> 1, wc = w & 1;
    int lr = l >> 4, lc = l & 15;

    if (t < 128) {
        int n = n0 + t;
        float L0 = Lbuf[(size_t)b * NN + n];
        float L1 = Lbuf[(size_t)NBNN + (size_t)b * NN + n];
        float M = fmaxf(L0, L1);
        float e0 = __expf(L0 - M), e1 = __expf(L1 - M);
        float inv = 1.0f / (e0 + e1);
        lw0[t] = e0 * inv; lw1[t] = e1 * inv;
    }
    __syncthreads();
    int row0 = t >> 2, row1 = (t >> 2) + 64;
    float w00 = lw0[row0], w10 = lw1[row0];
    float w01 = lw0[row1], w11 = lw1[row1];

    f32x4 acc[4][4];
    const f32x4 fz = {0.f, 0.f, 0.f, 0.f};
#pragma unroll
    for (int i = 0; i < 4; i++)
#pragma unroll
        for (int j = 0; j < 4; j++) acc[i][j] = fz;

    for (int kt = 0; kt < KCH / 32; kt++) {
        int c0 = kt * 32;
        __syncthreads();
#pragma unroll
        for (int p = 0; p < 4; p++) {
            int row = (t >> 3) + p * 32;
            int cc = (t & 7) * 4;
            float4 v = *(const float4*)&w_w[(size_t)(m0 + row) * KCH + c0 + cc];
            f16x4 h; h[0] = (F16)v.x; h[1] = (F16)v.y; h[2] = (F16)v.z; h[3] = (F16)v.w;
            *(f16x4*)&Al[row][cc] = h;
        }
#pragma unroll
        for (int p = 0; p < 2; p++) {
            int row = (p == 0) ? row0 : row1;
            float wa = (p == 0) ? w00 : w01;
            float wb2 = (p == 0) ? w10 : w11;
            int cc = (t & 3) * 8;
            size_t base = ((size_t)b * NN + n0 + row) * KCH + c0 + cc;
            f16x8 p0 = *(const f16x8*)&parts[base];
            f16x8 p1 = *(const f16x8*)&parts[PSET + base];
            f16x8 m;
#pragma unroll
            for (int j = 0; j < 8; j++)
                m[j] = (F16)(wa * (float)p0[j] + wb2 * (float)p1[j]);
            *(f16x8*)&Bl[row][cc] = m;
        }
        __syncthreads();
        f16x8 a[4];
#pragma unroll
        for (int fi = 0; fi < 4; fi++)
            a[fi] = *(f16x8*)&Al[wr * 64 + fi * 16 + lc][lr * 8];
#pragma unroll
        for (int fj = 0; fj < 4; fj++) {
            f16x8 bb = *(f16x8*)&Bl[wc * 64 + fj * 16 + lc][lr * 8];
#pragma unroll
            for (int fi = 0; fi < 4; fi++)
                acc[fi][fj] = __builtin_amdgcn_mfma_f32_16x16x32_f16(a[fi], bb, acc[fi][fj], 0, 0, 0);
        }
    }

#pragma unroll
    for (int fi = 0; fi < 4; fi++) {
        int o0 = m0 + wr * 64 + fi * 16 + lr * 4;
#pragma unroll
        for (int fj = 0; fj < 4; fj++) {
            int n = n0 + wc * 64 + fj * 16 + lc;
#pragma unroll
            for (int r = 0; r < 4; r++) {
                out[((size_t)b * OCH + o0 + r) * NN + n] = acc[fi][fj][r] + w_b[o0 + r];
            }
        }
    }
}

// ---------------------------------------------------------------- launch
extern "C" void kernel_launch(void* const* d_in, const int* in_sizes, int n_in,
                              void* d_out, int out_size, void* d_ws, size_t ws_size,
                              hipStream_t stream) {
    const float* x       = (const float*)d_in[0];
    const float* key_w   = (const float*)d_in[1];
    const float* key_b   = (const float*)d_in[2];
    const float* gamma   = (const float*)d_in[3];
    const float* beta    = (const float*)d_in[4];
    const float* mean    = (const float*)d_in[5];
    const float* var     = (const float*)d_in[6];
    const float* value_w = (const float*)d_in[7];
    const float* value_b = (const float*)d_in[8];
    const float* w_w     = (const float*)d_in[9];
    const float* w_b     = (const float*)d_in[10];
    float* out = (float*)d_out;
    char* ws = (char*)d_ws;

    // layout: parts 2*8.39M | KQt 8.39M | Vg 8.39M | L 128K | Mrow 64K | Mblk 1K
    size_t kqt_off  = 2 * PSET * 2;
    size_t vg_off   = kqt_off + 8388608ull;
    size_t l_off    = vg_off + 8388608ull;
    size_t mrow_off = l_off + (size_t)2 * NBNN * 4;
    size_t mblk_off = mrow_off + (size_t)NBNN * 4;

    F16*   parts = (F16*)(ws);
    F16*   KQt   = (F16*)(ws + kqt_off);
    F16*   Vg    = (F16*)(ws + vg_off);
    float* Lbuf  = (float*)(ws + l_off);
    float* Mrow  = (float*)(ws + mrow_off);
    float* Mblk  = (float*)(ws + mblk_off);

    hipLaunchKernelGGL(k_kv_gemm, dim3(32, 4, 4), dim3(256), 0, stream,
                       x, key_w, key_b, gamma, beta, mean, var, value_w, value_b, KQt, Vg);
    hipLaunchKernelGGL(k_rowmax, dim3(256), dim3(256), 0, stream, KQt, Mrow, Mblk);
    hipLaunchKernelGGL(k_flash, dim3(512), dim3(256), 0, stream,
                       KQt, Vg, Mrow, Mblk, parts, Lbuf);
    hipLaunchKernelGGL(k_out_gemm, dim3(32, 4, 4), dim3(256), 0, stream,
                       parts, Lbuf, w_w, w_b, out);
}

// Round 18
// 136.727 us; speedup vs baseline: 1.1083x; 1.0760x over previous
//
#include <hip/hip_runtime.h>

#define F16 _Float16
typedef _Float16 f16x8 __attribute__((ext_vector_type(8)));
typedef _Float16 f16x4 __attribute__((ext_vector_type(4)));
typedef float f32x4 __attribute__((ext_vector_type(4)));
typedef float f32x16 __attribute__((ext_vector_type(16)));

#define NB    4
#define CIN   512
#define NN    4096
#define KCH   256
#define OCH   512
#define BNEPS 1e-5f
#define PSET  ((size_t)NB * NN * KCH)        // elements per partial set
#define NBNN  (NB * NN)

// async global->LDS, 16B per lane (dest = wave-uniform base + lane*16)
__device__ __forceinline__ void gl16(const F16* g, F16* l) {
    __builtin_amdgcn_global_load_lds((const __attribute__((address_space(1))) void*)g,
                                     (__attribute__((address_space(3))) void*)l, 16, 0, 0);
}

// ---------------------------------------------------------------- K/V GEMM (direct x)
__global__ __launch_bounds__(256) void k_kv_gemm(
    const float* __restrict__ x,
    const float* __restrict__ key_w, const float* __restrict__ key_b,
    const float* __restrict__ gamma, const float* __restrict__ beta,
    const float* __restrict__ mean,  const float* __restrict__ var,
    const float* __restrict__ value_w, const float* __restrict__ value_b,
    F16* __restrict__ KQt, F16* __restrict__ Vg) {
    __shared__ F16 Al[128][40];
    __shared__ float Bs[32][134];
    int b = blockIdx.z;
    int m0 = blockIdx.y * 128;
    int n0 = blockIdx.x * 128;
    int t = threadIdx.x, w = t >> 6, l = t & 63;
    int wr = w >> 1, wc = w & 1;
    int lr = l >> 4, lc = l & 15;
    f32x4 acc[4][4];
    const f32x4 fz = {0.f, 0.f, 0.f, 0.f};
#pragma unroll
    for (int i = 0; i < 4; i++)
#pragma unroll
        for (int j = 0; j < 4; j++) acc[i][j] = fz;
    const float* xb = x + (size_t)b * CIN * NN;

    int bc = t >> 3;
    int nsub = ((t & 7) + bc) & 7;

    for (int kt = 0; kt < CIN / 32; kt++) {
        int c0 = kt * 32;
        __syncthreads();
#pragma unroll
        for (int p = 0; p < 4; p++) {
            int row = (t >> 3) + p * 32;
            int cc = (t & 7) * 4;
            int rg = m0 + row;
            const float* src = (rg < 256) ? (key_w + (size_t)rg * CIN)
                                          : (value_w + (size_t)(rg - 256) * CIN);
            float4 v = *(const float4*)&src[c0 + cc];
            f16x4 h; h[0] = (F16)v.x; h[1] = (F16)v.y; h[2] = (F16)v.z; h[3] = (F16)v.w;
            *(f16x4*)&Al[row][cc] = h;
        }
        {
            const float* xrow = xb + (size_t)(c0 + bc) * NN + n0 + nsub * 16;
#pragma unroll
            for (int p = 0; p < 4; p++) {
                float4 v = *(const float4*)&xrow[p * 4];
                int n = nsub * 16 + p * 4;
                *(float2*)&Bs[bc][n]     = make_float2(v.x, v.y);
                *(float2*)&Bs[bc][n + 2] = make_float2(v.z, v.w);
            }
        }
        __syncthreads();
        f16x8 a[4];
#pragma unroll
        for (int fi = 0; fi < 4; fi++)
            a[fi] = *(f16x8*)&Al[wr * 64 + fi * 16 + lc][lr * 8];
#pragma unroll
        for (int fj = 0; fj < 4; fj++) {
            int n = wc * 64 + fj * 16 + lc;
            f16x8 bb;
#pragma unroll
            for (int j = 0; j < 8; j++) bb[j] = (F16)Bs[lr * 8 + j][n];
#pragma unroll
            for (int fi = 0; fi < 4; fi++)
                acc[fi][fj] = __builtin_amdgcn_mfma_f32_16x16x32_f16(a[fi], bb, acc[fi][fj], 0, 0, 0);
        }
    }

    if (m0 < 256) {
#pragma unroll
        for (int fi = 0; fi < 4; fi++) {
            int ch0 = m0 + wr * 64 + fi * 16 + lr * 4;
            float invs[4], mns[4], bts[4], kbs[4];
#pragma unroll
            for (int r = 0; r < 4; r++) {
                int ch = ch0 + r;
                invs[r] = gamma[ch] * rsqrtf(var[ch] + BNEPS);
                mns[r] = mean[ch]; bts[r] = beta[ch]; kbs[r] = key_b[ch];
            }
#pragma unroll
            for (int fj = 0; fj < 4; fj++) {
                int n = n0 + wc * 64 + fj * 16 + lc;
                f16x4 o;
#pragma unroll
                for (int r = 0; r < 4; r++) {
                    float v = (acc[fi][fj][r] + kbs[r] - mns[r]) * invs[r] + bts[r];
                    v = fmaxf(v, 0.0f);
                    o[r] = (F16)v;
                }
                *(f16x4*)&KQt[((size_t)b * NN + n) * KCH + ch0] = o;
            }
        }
    } else {
#pragma unroll
        for (int fi = 0; fi < 4; fi++) {
            int v0 = m0 - 256 + wr * 64 + fi * 16 + lr * 4;
#pragma unroll
            for (int fj = 0; fj < 4; fj++) {
                int n = n0 + wc * 64 + fj * 16 + lc;
#pragma unroll
                for (int r = 0; r < 4; r++) {
                    float vv = acc[fi][fj][r] + value_b[v0 + r];
                    Vg[((size_t)b * KCH + v0 + r) * NN + n] = (F16)vv;
                }
            }
        }
    }
}

// ---------------------------------------------------------------- row norms + per-block max
__global__ __launch_bounds__(256) void k_rowmax(const F16* __restrict__ KQt,
                                                float* __restrict__ Mrow,
                                                float* __restrict__ Mblk) {
    __shared__ float wmax[4];
    int t = threadIdx.x;
    int r = blockIdx.x * 64 + (t >> 2);
    int part = t & 3;
    const F16* rp = KQt + (size_t)r * KCH + part * 64;
    float ss = 0.f;
#pragma unroll
    for (int i = 0; i < 8; i++) {
        f16x8 v = *(const f16x8*)&rp[i * 8];
#pragma unroll
        for (int j = 0; j < 8; j++) { float f = (float)v[j]; ss = fmaf(f, f, ss); }
    }
    ss += __shfl_xor(ss, 1, 64);
    ss += __shfl_xor(ss, 2, 64);
    float norm = sqrtf(ss);
    if (part == 0) Mrow[r] = norm;
    float mx = norm;
#pragma unroll
    for (int off = 4; off < 64; off <<= 1) mx = fmaxf(mx, __shfl_xor(mx, off, 64));
    if ((t & 63) == 0) wmax[t >> 6] = mx;
    __syncthreads();
    if (t == 0)
        Mblk[blockIdx.x] = fmaxf(fmaxf(wmax[0], wmax[1]), fmaxf(wmax[2], wmax[3]));
}

// ---------------------------------------------------------------- flash attention
// 64q/block, 4 waves, KVBLK=64, S=2, 512 blocks = 2/CU (LDS 72.3 KB), 32x32
// MFMA, fixed-bound softmax, zero-register pipeline: K(mt+1) streams into the
// dead Kl during PV; V(mt+1) streams into the dead Vl during the next QK.
__global__ __launch_bounds__(256, 2) void k_flash(const F16* __restrict__ KQt,
                                                  const F16* __restrict__ Vg,
                                                  const float* __restrict__ Mrow,
                                                  const float* __restrict__ Mblk,
                                                  F16* __restrict__ parts,
                                                  float* __restrict__ Lbuf) {
    __shared__ __align__(16) F16 Kl[64 * 256];    // 32 KB linear (src-swizzled)
    __shared__ __align__(16) F16 Vl[256 * 64];    // 32 KB linear (src-swizzled)
    __shared__ __align__(16) F16 Ps[64 * 64];     //  8 KB swizzled
    __shared__ __align__(16) float crl[64];
    int bid = blockIdx.x;
    int xcd = bid & 7;
    int b = xcd >> 1;
    int hi = bid >> 3;
    int kset = hi & 1;
    int qtile = (xcd & 1) * 32 + (hi >> 1);
    int n0 = qtile * 64;
    int kbase = kset * 2048;
    int t = threadIdx.x, w = t >> 6, l = t & 63;
    int l31 = l & 31, lh = l >> 5;
    int x7 = l31 & 7;
    int qg = w >> 1, kh = w & 1;
    const F16* kqb = KQt + (size_t)b * NN * KCH;
    const F16* vgb = Vg + (size_t)b * KCH * NN;
    const float scale = 0.0625f;

#define STAGE_K(m0_)                                                            \
    {                                                                           \
        _Pragma("unroll") for (int c = 0; c < 8; c++) {                         \
            int row = c * 8 + (t >> 5);                                         \
            gl16(kqb + (size_t)((m0_) + row) * KCH + ((t & 31) ^ (t >> 5)) * 8, \
                 &Kl[c * 2048 + w * 512]);                                      \
        }                                                                       \
    }
#define STAGE_V(m0_)                                                            \
    {                                                                           \
        _Pragma("unroll") for (int c = 0; c < 8; c++) {                         \
            int vrow = c * 32 + (t >> 3);                                       \
            gl16(vgb + (size_t)vrow * NN + (m0_) + ((t & 7) ^ ((t >> 3) & 7)) * 8, \
                 &Vl[c * 2048 + w * 512]);                                      \
        }                                                                       \
    }

    // ---- prologue: stage tile 0 (latency covered by Q/m loads below) ----
    STAGE_K(kbase);
    STAGE_V(kbase);

    f16x8 qA[16];
    {
        const F16* qp = kqb + (size_t)(n0 + qg * 32 + l31) * KCH + lh * 8;
#pragma unroll
        for (int cs = 0; cs < 16; cs++) qA[cs] = *(const f16x8*)&qp[cs * 16];
    }
    float mb;
    {
        float v = Mblk[b * 64 + l];
#pragma unroll
        for (int off = 1; off < 64; off <<= 1) v = fmaxf(v, __shfl_xor(v, off, 64));
        mb = v;
    }
    float mbv = mb * scale;
    f32x4 m4[4];
    {
        const float* mp = Mrow + (size_t)b * NN + n0 + qg * 32 + lh * 4;
#pragma unroll
        for (int g = 0; g < 4; g++) {
            f32x4 v = *(const f32x4*)&mp[g * 8];
#pragma unroll
            for (int j = 0; j < 4; j++) m4[g][j] = v[j] * mbv;
        }
    }
    f16x8 one8;
#pragma unroll
    for (int j = 0; j < 8; j++) one8[j] = (F16)1.0f;

    f32x16 acc[2][2] = {};
    f32x16 lsum = {};

    __syncthreads();                   // drain: K(0), V(0) visible

    for (int mt = 0; mt < 32; mt++) {
        // ---- QK: S(32q x 32k), contraction 256 ----
        f32x16 s = {};
#pragma unroll
        for (int cs = 0; cs < 16; cs++) {
            f16x8 kB = *(f16x8*)&Kl[(kh * 32 + l31) * 256 + (((cs * 2 + lh) ^ x7) * 8)];
            s = __builtin_amdgcn_mfma_f32_32x32x16_f16(qA[cs], kB, s, 0, 0, 0);
        }
        // ---- P = exp(S*scale - m_row) -> Ps ----
#pragma unroll
        for (int r = 0; r < 16; r++) {
            int row = qg * 32 + (r & 3) + 8 * (r >> 2) + 4 * lh;
            float p = __expf(fmaf(s[r], scale, -m4[r >> 2][r & 3]));
            int chs = (kh * 4 + (l31 >> 3)) ^ (row & 7);
            Ps[row * 64 + chs * 8 + (l31 & 7)] = (F16)p;
        }
        __syncthreads();               // B_P: P visible; V(mt) drained; Kl dead

        // ---- prefetch K(mt+1) into Kl; PV covers its latency ----
        if (mt < 31) STAGE_K(kbase + (mt + 1) * 64);

        // ---- PV (wave's 64-v slice over 64 q) + lsum ----
#pragma unroll
        for (int kc = 0; kc < 4; kc++) {
            f16x8 pa0 = *(f16x8*)&Ps[l31 * 64 + (((kc * 2 + lh) ^ x7) * 8)];
            f16x8 pa1 = *(f16x8*)&Ps[(32 + l31) * 64 + (((kc * 2 + lh) ^ x7) * 8)];
            if (kh == 0)
                lsum = __builtin_amdgcn_mfma_f32_32x32x16_f16(qg == 0 ? pa0 : pa1,
                                                              one8, lsum, 0, 0, 0);
#pragma unroll
            for (int vh = 0; vh < 2; vh++) {
                int vr = w * 64 + vh * 32 + l31;
                f16x8 vb = *(f16x8*)&Vl[vr * 64 + (((kc * 2 + lh) ^ x7) * 8)];
                acc[0][vh] = __builtin_amdgcn_mfma_f32_32x32x16_f16(pa0, vb, acc[0][vh], 0, 0, 0);
                acc[1][vh] = __builtin_amdgcn_mfma_f32_32x32x16_f16(pa1, vb, acc[1][vh], 0, 0, 0);
            }
        }
        __syncthreads();               // B_end: K(mt+1) drained; Vl/Ps dead

        // ---- prefetch V(mt+1) into Vl; next QK covers its latency ----
        if (mt < 31) STAGE_V(kbase + (mt + 1) * 64);
    }
#undef STAGE_K
#undef STAGE_V

    // epilogue: broadcast lsum, write normalized partial + L = m + ln(l)
    if (kh == 0 && l31 == 0) {
#pragma unroll
        for (int r = 0; r < 16; r++)
            crl[qg * 32 + (r & 3) + 8 * (r >> 2) + 4 * lh] = lsum[r];
    }
    __syncthreads();

    F16* cb = parts + (size_t)kset * PSET + (size_t)b * NN * KCH;
#pragma unroll
    for (int qg2 = 0; qg2 < 2; qg2++) {
        f32x4 iv[4];
#pragma unroll
        for (int g = 0; g < 4; g++) {
            f32x4 lv = *(f32x4*)&crl[qg2 * 32 + g * 8 + lh * 4];
#pragma unroll
            for (int j = 0; j < 4; j++) iv[g][j] = 1.0f / lv[j];
        }
#pragma unroll
        for (int vh = 0; vh < 2; vh++) {
#pragma unroll
            for (int r = 0; r < 16; r++) {
                int n = n0 + qg2 * 32 + (r & 3) + 8 * (r >> 2) + 4 * lh;
                cb[(size_t)n * KCH + w * 64 + vh * 32 + l31] =
                    (F16)(acc[qg2][vh][r] * iv[r >> 2][r & 3]);
            }
        }
    }
    float* Lb = Lbuf + ((size_t)kset * NB + b) * NN;
    if (kh == 0 && l31 == 0) {
#pragma unroll
        for (int r = 0; r < 16; r++) {
            int n = n0 + qg * 32 + (r & 3) + 8 * (r >> 2) + 4 * lh;
            Lb[n] = m4[r >> 2][r & 3] + __logf(lsum[r]);
        }
    }
}

// ---------------------------------------------------------------- out GEMM (fused split-K merge)
__global__ __launch_bounds__(256) void k_out_gemm(const F16* __restrict__ parts,
                                                  const float* __restrict__ Lbuf,
                                                  const float* __restrict__ w_w,
                                                  const float* __restrict__ w_b,
                                                  float* __restrict__ out) {
    __shared__ F16 Al[128][40];
    __shared__ F16 Bl[128][40];
    __shared__ float lw0[128], lw1[128];
    int b = blockIdx.z;
    int m0 = blockIdx.y * 128;
    int n0 = blockIdx.x * 128;
    int t = threadIdx.x, w = t >> 6, l = t & 63;
    int wr = w >> 1, wc = w & 1;
    int lr = l >> 4, lc = l & 15;

    if (t < 128) {
        int n = n0 + t;
        float L0 = Lbuf[(size_t)b * NN + n];
        float L1 = Lbuf[(size_t)NBNN + (size_t)b * NN + n];
        float M = fmaxf(L0, L1);
        float e0 = __expf(L0 - M), e1 = __expf(L1 - M);
        float inv = 1.0f / (e0 + e1);
        lw0[t] = e0 * inv; lw1[t] = e1 * inv;
    }
    __syncthreads();
    int row0 = t >> 2, row1 = (t >> 2) + 64;
    float w00 = lw0[row0], w10 = lw1[row0];
    float w01 = lw0[row1], w11 = lw1[row1];

    f32x4 acc[4][4];
    const f32x4 fz = {0.f, 0.f, 0.f, 0.f};
#pragma unroll
    for (int i = 0; i < 4; i++)
#pragma unroll
        for (int j = 0; j < 4; j++) acc[i][j] = fz;

    for (int kt = 0; kt < KCH / 32; kt++) {
        int c0 = kt * 32;
        __syncthreads();
#pragma unroll
        for (int p = 0; p < 4; p++) {
            int row = (t >> 3) + p * 32;
            int cc = (t & 7) * 4;
            float4 v = *(const float4*)&w_w[(size_t)(m0 + row) * KCH + c0 + cc];
            f16x4 h; h[0] = (F16)v.x; h[1] = (F16)v.y; h[2] = (F16)v.z; h[3] = (F16)v.w;
            *(f16x4*)&Al[row][cc] = h;
        }
#pragma unroll
        for (int p = 0; p < 2; p++) {
            int row = (p == 0) ? row0 : row1;
            float wa = (p == 0) ? w00 : w01;
            float wb2 = (p == 0) ? w10 : w11;
            int cc = (t & 3) * 8;
            size_t base = ((size_t)b * NN + n0 + row) * KCH + c0 + cc;
            f16x8 p0 = *(const f16x8*)&parts[base];
            f16x8 p1 = *(const f16x8*)&parts[PSET + base];
            f16x8 m;
#pragma unroll
            for (int j = 0; j < 8; j++)
                m[j] = (F16)(wa * (float)p0[j] + wb2 * (float)p1[j]);
            *(f16x8*)&Bl[row][cc] = m;
        }
        __syncthreads();
        f16x8 a[4];
#pragma unroll
        for (int fi = 0; fi < 4; fi++)
            a[fi] = *(f16x8*)&Al[wr * 64 + fi * 16 + lc][lr * 8];
#pragma unroll
        for (int fj = 0; fj < 4; fj++) {
            f16x8 bb = *(f16x8*)&Bl[wc * 64 + fj * 16 + lc][lr * 8];
#pragma unroll
            for (int fi = 0; fi < 4; fi++)
                acc[fi][fj] = __builtin_amdgcn_mfma_f32_16x16x32_f16(a[fi], bb, acc[fi][fj], 0, 0, 0);
        }
    }

#pragma unroll
    for (int fi = 0; fi < 4; fi++) {
        int o0 = m0 + wr * 64 + fi * 16 + lr * 4;
#pragma unroll
        for (int fj = 0; fj < 4; fj++) {
            int n = n0 + wc * 64 + fj * 16 + lc;
#pragma unroll
            for (int r = 0; r < 4; r++) {
                out[((size_t)b * OCH + o0 + r) * NN + n] = acc[fi][fj][r] + w_b[o0 + r];
            }
        }
    }
}

// ---------------------------------------------------------------- launch
extern "C" void kernel_launch(void* const* d_in, const int* in_sizes, int n_in,
                              void* d_out, int out_size, void* d_ws, size_t ws_size,
                              hipStream_t stream) {
    const float* x       = (const float*)d_in[0];
    const float* key_w   = (const float*)d_in[1];
    const float* key_b   = (const float*)d_in[2];
    const float* gamma   = (const float*)d_in[3];
    const float* beta    = (const float*)d_in[4];
    const float* mean    = (const float*)d_in[5];
    const float* var     = (const float*)d_in[6];
    const float* value_w = (const float*)d_in[7];
    const float* value_b = (const float*)d_in[8];
    const float* w_w     = (const float*)d_in[9];
    const float* w_b     = (const float*)d_in[10];
    float* out = (float*)d_out;
    char* ws = (char*)d_ws;

    // layout: parts 2*8.39M | KQt 8.39M | Vg 8.39M | L 128K | Mrow 64K | Mblk 1K
    size_t kqt_off  = 2 * PSET * 2;
    size_t vg_off   = kqt_off + 8388608ull;
    size_t l_off    = vg_off + 8388608ull;
    size_t mrow_off = l_off + (size_t)2 * NBNN * 4;
    size_t mblk_off = mrow_off + (size_t)NBNN * 4;

    F16*   parts = (F16*)(ws);
    F16*   KQt   = (F16*)(ws + kqt_off);
    F16*   Vg    = (F16*)(ws + vg_off);
    float* Lbuf  = (float*)(ws + l_off);
    float* Mrow  = (float*)(ws + mrow_off);
    float* Mblk  = (float*)(ws + mblk_off);

    hipLaunchKernelGGL(k_kv_gemm, dim3(32, 4, 4), dim3(256), 0, stream,
                       x, key_w, key_b, gamma, beta, mean, var, value_w, value_b, KQt, Vg);
    hipLaunchKernelGGL(k_rowmax, dim3(256), dim3(256), 0, stream, KQt, Mrow, Mblk);
    hipLaunchKernelGGL(k_flash, dim3(512), dim3(256), 0, stream,
                       KQt, Vg, Mrow, Mblk, parts, Lbuf);
    hipLaunchKernelGGL(k_out_gemm, dim3(32, 4, 4), dim3(256), 0, stream,
                       parts, Lbuf, w_w, w_b, out);
}